// Round 9
// baseline (191.016 us; speedup 1.0000x reference)
//
#include <hip/hip_runtime.h>

// Problem constants (from reference): B=8, E=512, L=4096, D=256, all fp32.
#define B_N 8
#define E_N 512
#define L_N 4096
#define D_N 256

#define SPLITK 8
#define KC_LEN (L_N / SPLITK)   // 512
#define BK 64
#define KC_ITERS (KC_LEN / BK)  // 8

#define ET 64                   // E tile
#define DT 128                  // D tile
#define NTHREADS 512

#define SLICE_ELEMS (B_N * E_N * D_N)           // 1M floats = 4 MB per split slice

typedef __attribute__((ext_vector_type(8))) short short8;   // 8 bf16 (MFMA A/B frag)
typedef __attribute__((ext_vector_type(4))) float f32x4;    // MFMA acc / global float4
typedef __attribute__((ext_vector_type(2))) unsigned int uint2v; // 2x packed bf16 pair
typedef __attribute__((ext_vector_type(4))) unsigned int uint4v; // 4x packed bf16 pair

// Packed fp32x2 -> bf16x2 (RNE) in ONE VALU op (R4: VALUBusy 14% -> 4.4%).
__device__ __forceinline__ unsigned cvt_pk_bf16(float lo, float hi) {
    unsigned r;
    asm("v_cvt_pk_bf16_f32 %0, %1, %2" : "=v"(r) : "v"(lo), "v"(hi));
    return r;
}

// LDS tile: [row][64 k] bf16, 128 B per row, NO pad. 16B-chunk XOR swizzle
// (verified R2: SQ_LDS_BANK_CONFLICT 5.2M -> 0). k multiple of 4 at call sites.
__device__ __forceinline__ int swz(int row, int k) {
    return row * 64 + ((((k >> 3) ^ (row & 7)) << 3) | (k & 7));
}

// ---------------- Stage 1: split-K partial GEMM, NO atomics ----------------
// R8 structural change: A (map) is NOT staged in LDS. The 16x16x32 A-fragment
// is contiguous along l in map's [E,L] layout -> per-lane global dwordx4 +
// cvt_pk builds af directly. Only B (doc) needs the LDS transpose. This
// removes the A-LDS writes/reads, one barrier per iter (B double-buffered,
// single-barrier is race-free: writes(it+1) hit buf[it+1&1], and all waves
// passed barrier(it) after their buf[it&1] reads completed), and the register
// liveness that spilled (R4/R5) or collapsed to serial (R1/R6).
// vmcnt ordering (in-order counter!): per iter issue A(it) THEN B(it+1), so
// consuming A waits vmcnt(4) and leaves the B prefetch in flight a full iter.
// FAILED, do not repeat: (512,8) VGPR crush (R5, WRITE 285MB); distance-2 reg
// pipeline (R4, WRITE 104MB); 4 blocks/CU via small tiles (R7, slower).
__global__ __launch_bounds__(NTHREADS, 4)
void mp_gemm(const float* __restrict__ doc,   // [B, L, D]
             const float* __restrict__ map,   // [B, E, L]
             float* __restrict__ ws)          // [SPLITK, B, E, D] partials
{
    __shared__ unsigned short Bs[2][DT * 64];   // doc tile transposed, 2x16KB

    // XCD-chunked swizzle: each XCD owns 128 consecutive w = 8 complete (b,kc)
    // groups; a group's 16 tiles share doc/map panels in that XCD's L2.
    const int p    = (int)blockIdx.x;            // 0..1023
    const int w    = ((p & 7) << 7) | (p >> 3);
    const int tile = w & 15;       // et*2 + dt
    const int grp  = w >> 4;       // 0..63
    const int b    = grp & 7;
    const int kc   = grp >> 3;     // 0..7

    const int e0  = (tile >> 1) * ET;   // 8 E tiles
    const int d0  = (tile & 1) * DT;    // 2 D tiles
    const int kc0 = kc * KC_LEN;

    const float* docB = doc + (size_t)b * L_N * D_N;
    const float* mapB = map + (size_t)b * E_N * L_N;
    float* wsB = ws + (size_t)kc * SLICE_ELEMS + (size_t)b * E_N * D_N;

    const int tid  = threadIdx.x;
    const int lane = tid & 63;
    const int wave = tid >> 6;     // 0..7

    // ---- B staging (identical pattern to R6/R7: verified coalesced + 0-conflict)
    const int kb = tid & 15;       // k block: varies across lanes (LDS chunk spread)
    const int nb = tid >> 4;       // n block (0..31)
    f32x4 br[4];

    #define LOAD_B(K0)                                                                     \
        do {                                                                               \
            _Pragma("unroll")                                                              \
            for (int i = 0; i < 4; ++i)                                                    \
                br[i] = *(const f32x4*)(docB + (size_t)((K0) + kb * 4 + i) * D_N +         \
                                        d0 + nb * 4);                                      \
        } while (0)

    // ---- compute setup: 8 waves in 2(m) x 4(n) grid; each wave 32x32 output ----
    const int wm = wave >> 2;      // 0..1 : 32-row block
    const int wn = wave & 3;       // 0..3 : 32-col block
    const int fm = lane & 15;
    const int q  = lane >> 4;

    // A-fragment global base: lane (q,fm) reads map[e0+wm*32+mi*16+fm][k + q*8 ..+8]
    const float* aBase = mapB + (size_t)(e0 + wm * 32 + fm) * L_N + q * 8;
    f32x4 arf[8];                  // 2 kk x 2 mi x 2 halves (32 VGPRs, short-lived)

    #define LOAD_A(K0)                                                                     \
        do {                                                                               \
            _Pragma("unroll")                                                              \
            for (int kk = 0; kk < 2; ++kk)                                                 \
                _Pragma("unroll")                                                          \
                for (int mi = 0; mi < 2; ++mi) {                                           \
                    const float* ap = aBase + (size_t)(mi * 16) * L_N + (K0) + kk * 32;    \
                    arf[kk * 4 + mi * 2 + 0] = *(const f32x4*)(ap);                        \
                    arf[kk * 4 + mi * 2 + 1] = *(const f32x4*)(ap + 4);                    \
                }                                                                          \
        } while (0)

    f32x4 acc[2][2] = {};

    LOAD_B(kc0);                   // prologue: B tile-0 in flight

    for (int it = 0; it < KC_ITERS; ++it) {
        const int bi = it & 1;

        // Convert + stage B(it) to LDS buf[bi] (vmcnt(0) wait lands here).
        #pragma unroll
        for (int j = 0; j < 4; ++j) {
            uint2v wv;
            wv[0] = cvt_pk_bf16(br[0][j], br[1][j]);
            wv[1] = cvt_pk_bf16(br[2][j], br[3][j]);
            *(uint2v*)&Bs[bi][swz(nb * 4 + j, kb * 4)] = wv;
        }

        // Issue A(it) FIRST, then B(it+1): A is consumed via vmcnt(4)/(8)
        // counted waits, leaving the 4 B loads in flight a full iteration.
        LOAD_A(kc0 + it * BK);
        if (it + 1 < KC_ITERS) LOAD_B(kc0 + (it + 1) * BK);
        __builtin_amdgcn_sched_barrier(0);

        // Single barrier per iter: buf[bi] writes visible; LDS-only wait so
        // the global loads stay in flight across it.
        asm volatile("s_waitcnt lgkmcnt(0)" ::: "memory");
        __builtin_amdgcn_s_barrier();
        __builtin_amdgcn_sched_barrier(0);

        // MFMA phase: A-frags from regs (global->cvt), B-frags from LDS.
        __builtin_amdgcn_s_setprio(1);
        #pragma unroll
        for (int kk = 0; kk < 2; ++kk) {
            short8 af[2], bf[2];
            #pragma unroll
            for (int mi = 0; mi < 2; ++mi) {
                const f32x4 a0 = arf[kk * 4 + mi * 2 + 0];
                const f32x4 a1 = arf[kk * 4 + mi * 2 + 1];
                uint4v aw;
                aw[0] = cvt_pk_bf16(a0[0], a0[1]);
                aw[1] = cvt_pk_bf16(a0[2], a0[3]);
                aw[2] = cvt_pk_bf16(a1[0], a1[1]);
                aw[3] = cvt_pk_bf16(a1[2], a1[3]);
                af[mi] = __builtin_bit_cast(short8, aw);
            }
            #pragma unroll
            for (int ni = 0; ni < 2; ++ni) {
                const int n = wn * 32 + ni * 16 + fm;
                bf[ni] = *(const short8*)&Bs[bi][swz(n, kk * 32 + q * 8)];
            }
            #pragma unroll
            for (int mi = 0; mi < 2; ++mi)
                #pragma unroll
                for (int ni = 0; ni < 2; ++ni)
                    acc[mi][ni] = __builtin_amdgcn_mfma_f32_16x16x32_bf16(
                        af[mi], bf[ni], acc[mi][ni], 0, 0, 0);
        }
        __builtin_amdgcn_s_setprio(0);
        // No second barrier needed: next iter writes buf[bi^1]; buf[bi] is
        // next overwritten at it+2, after every wave passed barrier(it+1),
        // by which time their buf[bi] ds_reads (waited before MFMA) are done.
    }
    #undef LOAD_A
    #undef LOAD_B

    // ---- epilogue: plain stores of the partial tile to this block's private
    // workspace slice. C/D layout: col = lane&15, row = (lane>>4)*4 + i.
    #pragma unroll
    for (int mi = 0; mi < 2; ++mi) {
        const int rLoc = wm * 32 + mi * 16 + q * 4;
        #pragma unroll
        for (int ni = 0; ni < 2; ++ni) {
            const int c = d0 + wn * 32 + ni * 16 + fm;
            #pragma unroll
            for (int i = 0; i < 4; ++i) {
                const int rr = rLoc + i;
                wsB[(size_t)(e0 + rr) * D_N + c] = acc[mi][ni][i];
            }
        }
    }
}

// ---------------- Stage 2: reduce slices + scale by 1/len ----------------
__global__ __launch_bounds__(256)
void mp_reduce(const float* __restrict__ ws,    // [SPLITK, B*E*D]
               const float* __restrict__ lens,  // [B, E]
               float* __restrict__ out)         // [B*E*D]
{
    const int t = (int)blockIdx.x * 256 + (int)threadIdx.x;  // float4 index
    const size_t off = (size_t)t * 4;
    const int be = t >> 6;            // D/4 = 64 float4 per (b,e) row

    f32x4 s = {};
    #pragma unroll
    for (int k = 0; k < SPLITK; ++k) {
        const f32x4 v = *(const f32x4*)(ws + (size_t)k * SLICE_ELEMS + off);
        s += v;
    }
    const float il = 1.0f / lens[be];
    s *= il;
    *(f32x4*)(out + off) = s;
}

extern "C" void kernel_launch(void* const* d_in, const int* in_sizes, int n_in,
                              void* d_out, int out_size, void* d_ws, size_t ws_size,
                              hipStream_t stream) {
    const float* doc  = (const float*)d_in[0];  // doc_state [B,L,D]
    const float* map  = (const float*)d_in[1];  // entity_mapping [B,E,L]
    const float* lens = (const float*)d_in[2];  // entity_lens [B,E]
    float* out = (float*)d_out;                 // [B,E,D] fp32
    float* ws  = (float*)d_ws;                  // needs 32 MB (SPLITK slices)

    // No memset needed: stage 1 fully writes every ws element, stage 2 fully
    // overwrites out.
    dim3 grid1(SPLITK * 16 * B_N);  // 1024 blocks: 16 tiles x 8 b x 8 kc
    mp_gemm<<<grid1, NTHREADS, 0, stream>>>(doc, map, ws);

    dim3 grid2(SLICE_ELEMS / 4 / 256);  // 1024 blocks
    mp_reduce<<<grid2, 256, 0, stream>>>(ws, lens, out);
}

// Round 10
// 141.456 us; speedup vs baseline: 1.3504x; 1.3504x over previous
//
#include <hip/hip_runtime.h>

// Problem constants (from reference): B=8, E=512, L=4096, D=256, all fp32.
#define B_N 8
#define E_N 512
#define L_N 4096
#define D_N 256

#define SPLITK 8
#define KC_LEN (L_N / SPLITK)   // 512
#define BKF 32                  // K per iteration (fp32 tiles)
#define KC_ITERS (KC_LEN / BKF) // 16

#define ET 128                  // E tile
#define DT 128                  // D tile
#define NTHREADS 512

#define SLICE_ELEMS (B_N * E_N * D_N)           // 1M floats = 4 MB per split slice

typedef __attribute__((ext_vector_type(8))) short short8;   // 8 bf16 (MFMA A/B frag)
typedef __attribute__((ext_vector_type(4))) float f32x4;    // MFMA acc / global float4
typedef __attribute__((ext_vector_type(4))) unsigned int uint4v; // 4x packed bf16 pair

// Packed fp32x2 -> bf16x2 (RNE) in ONE VALU op (R4: VALUBusy 14% -> 4.4%).
__device__ __forceinline__ unsigned cvt_pk_bf16(float lo, float hi) {
    unsigned r;
    asm("v_cvt_pk_bf16_f32 %0, %1, %2" : "=v"(r) : "v"(lo), "v"(hi));
    return r;
}

// ---------------- Stage 1: split-K partial GEMM ----------------
// R10: staging via __builtin_amdgcn_global_load_lds (width 16). Rationale:
// every register-staged prefetch in R1-R9 either spilled (R4/R5) or was
// silently SUNK to its use point by the compiler (R1/R6/R9: VGPR_Count < live
// set each time), serializing load latency into every iteration. gload_lds
// has NO VGPR destination: it cannot be sunk, costs zero registers, and its
// completion is tracked by a counted vmcnt — the loads provably stay in
// flight across the whole previous MFMA phase. Tiles are staged as FP32
// (gload_lds can't convert); fp32->bf16 moves to fragment-read time (cvt_pk,
// ~24 VALU/iter/lane — VALU is 8% busy, free).
// LDS swizzles are T21-correct: linear gload_lds dest + inverse-swizzled
// GLOBAL source + swizzled read (both-sides-or-neither).
//   A [m][k]: 128B rows, 16B chunk ^ (m&7)  (kills 16-way column-read conflict)
//   B [k][n]: 512B rows, 16B chunk ^ (q<<2), q=k>>3 (q-groups spread; 2-way free)
// FAILED, do not repeat: (512,8) VGPR crush (R5); distance-2 reg pipeline
// (R4); A-direct-from-global (R9, 95us); 4 blocks/CU small tiles (R7).
__global__ __launch_bounds__(NTHREADS, 4)
void mp_gemm(const float* __restrict__ doc,   // [B, L, D]
             const float* __restrict__ map,   // [B, E, L]
             float* __restrict__ ws)          // [SPLITK, B, E, D] partials
{
    __shared__ float Afp[2][ET * BKF];   // [m][k-swz] fp32, 16KB per buf
    __shared__ float Bfp[2][BKF * DT];   // [k][n-swz] fp32, 16KB per buf

    // XCD-chunked swizzle (R6): each XCD owns 8 complete (b,kc) groups whose
    // 8 tiles share doc/map panels in that XCD's L2.
    const int p    = (int)blockIdx.x;            // 0..511
    const int w    = ((p & 7) << 6) | (p >> 3);
    const int tile = w & 7;        // et*2 + dt
    const int grp  = w >> 3;       // 0..63
    const int b    = grp & 7;
    const int kc   = grp >> 3;     // 0..7

    const int e0  = (tile >> 1) * ET;   // 4 E tiles
    const int d0  = (tile & 1) * DT;    // 2 D tiles
    const int kc0 = kc * KC_LEN;

    const float* docB = doc + (size_t)b * L_N * D_N;
    const float* mapB = map + (size_t)b * E_N * L_N;
    float* wsB = ws + (size_t)kc * SLICE_ELEMS + (size_t)b * E_N * D_N;

    const int tid  = threadIdx.x;
    const int lane = tid & 63;
    const int wave = tid >> 6;     // 0..7

    // Per-thread staging coordinates (linear LDS = base + lane*16B):
    //   A call c: LDS byte = c*8192 + tid*16 -> row m = c*64 + (tid>>3),
    //             chunk = tid&7. Source chunk = chunk ^ (m&7).
    //   B call c: row k = c*16 + (tid>>5), chunk = tid&31.
    //             Source chunk = chunk ^ ((k>>3)<<2).
    const int aRow = tid >> 3;       // + c*64
    const int aChk = tid & 7;
    const int bRow = tid >> 5;       // + c*16
    const int bChk = tid & 31;
    const int wbase = wave * 256;    // wave's 1KB (256 floats) within a call

    #define STAGE(BI, K0)                                                                  \
        do {                                                                               \
            _Pragma("unroll")                                                              \
            for (int c = 0; c < 2; ++c) {                                                  \
                const int am = c * 64 + aRow;                                              \
                const float* gA = mapB + (size_t)(e0 + am) * L_N + (K0) +                  \
                                  ((aChk ^ (am & 7)) << 2);                                \
                __builtin_amdgcn_global_load_lds(gA, &Afp[BI][c * 2048 + wbase],           \
                                                 16, 0, 0);                                \
                const int bk = c * 16 + bRow;                                              \
                const float* gB = docB + (size_t)((K0) + bk) * D_N + d0 +                  \
                                  ((bChk ^ ((bk >> 3) << 2)) << 2);                        \
                __builtin_amdgcn_global_load_lds(gB, &Bfp[BI][c * 2048 + wbase],           \
                                                 16, 0, 0);                                \
            }                                                                              \
        } while (0)

    // ---- compute setup: 8 waves in 2(m) x 4(n) grid; each wave 64x32 output ----
    const int wm = wave >> 2;      // 0..1 : 64-row block
    const int wn = wave & 3;       // 0..3 : 32-col block
    const int fm = lane & 15;
    const int q  = lane >> 4;

    f32x4 acc[4][2] = {};

    STAGE(0, kc0);                 // prologue: tile 0 -> buf0 (4 loads in flight)

    for (int it = 0; it < KC_ITERS; ++it) {
        const int cur = it & 1;

        // Issue next tile FIRST (into the buffer read last iter -- safe: end
        // barrier of it-1 guaranteed all reads done). Last iter: clamp to kc0
        // (harmless dummy reload, keeps vmcnt arithmetic uniform, no OOB).
        const int k0n = (it + 1 < KC_ITERS) ? kc0 + (it + 1) * BKF : kc0;
        STAGE(cur ^ 1, k0n);
        __builtin_amdgcn_sched_barrier(0);

        // Counted wait: drain cur's 4 loads (issued one full iteration ago),
        // leave the 4 just-issued in flight. Never vmcnt(0) in the loop.
        asm volatile("s_waitcnt vmcnt(4)" ::: "memory");
        __builtin_amdgcn_sched_barrier(0);
        __builtin_amdgcn_s_barrier();          // all waves' cur parts landed
        __builtin_amdgcn_sched_barrier(0);

        // MFMA phase: fp32 frags from LDS, cvt_pk -> bf16, 8 MFMA.
        __builtin_amdgcn_s_setprio(1);
        short8 af[4], bf[2];
        #pragma unroll
        for (int mi = 0; mi < 4; ++mi) {
            const int m = wm * 64 + mi * 16 + fm;
            const int mb = m * BKF;
            const f32x4 lo = *(const f32x4*)&Afp[cur][mb + (((2 * q)     ^ (m & 7)) << 2)];
            const f32x4 hi = *(const f32x4*)&Afp[cur][mb + (((2 * q + 1) ^ (m & 7)) << 2)];
            uint4v aw;
            aw[0] = cvt_pk_bf16(lo[0], lo[1]);
            aw[1] = cvt_pk_bf16(lo[2], lo[3]);
            aw[2] = cvt_pk_bf16(hi[0], hi[1]);
            aw[3] = cvt_pk_bf16(hi[2], hi[3]);
            af[mi] = __builtin_bit_cast(short8, aw);
        }
        #pragma unroll
        for (int ni = 0; ni < 2; ++ni) {
            const int n  = wn * 32 + ni * 16 + fm;
            const int cc = (((n >> 2) ^ (q << 2)) << 2) + (n & 3);
            float v[8];
            #pragma unroll
            for (int j = 0; j < 8; ++j)
                v[j] = Bfp[cur][(q * 8 + j) * DT + cc];
            uint4v bw;
            bw[0] = cvt_pk_bf16(v[0], v[1]);
            bw[1] = cvt_pk_bf16(v[2], v[3]);
            bw[2] = cvt_pk_bf16(v[4], v[5]);
            bw[3] = cvt_pk_bf16(v[6], v[7]);
            bf[ni] = __builtin_bit_cast(short8, bw);
        }
        #pragma unroll
        for (int mi = 0; mi < 4; ++mi)
            #pragma unroll
            for (int ni = 0; ni < 2; ++ni)
                acc[mi][ni] = __builtin_amdgcn_mfma_f32_16x16x32_bf16(
                    af[mi], bf[ni], acc[mi][ni], 0, 0, 0);
        __builtin_amdgcn_s_setprio(0);

        // End barrier: all waves' reads of buf[cur] complete before next
        // iter's STAGE overwrites it. sched_barrier: raw s_barrier is not a
        // compiler fence.
        __builtin_amdgcn_s_barrier();
        __builtin_amdgcn_sched_barrier(0);
    }
    #undef STAGE

    // ---- epilogue: plain stores of the partial tile to this block's private
    // workspace slice. C/D layout: col = lane&15, row = (lane>>4)*4 + i.
    #pragma unroll
    for (int mi = 0; mi < 4; ++mi) {
        const int rLoc = wm * 64 + mi * 16 + q * 4;
        #pragma unroll
        for (int ni = 0; ni < 2; ++ni) {
            const int c = d0 + wn * 32 + ni * 16 + fm;
            #pragma unroll
            for (int i = 0; i < 4; ++i) {
                const int rr = rLoc + i;
                wsB[(size_t)(e0 + rr) * D_N + c] = acc[mi][ni][i];
            }
        }
    }
}

// ---------------- Stage 2: reduce slices + scale by 1/len ----------------
__global__ __launch_bounds__(256)
void mp_reduce(const float* __restrict__ ws,    // [SPLITK, B*E*D]
               const float* __restrict__ lens,  // [B, E]
               float* __restrict__ out)         // [B*E*D]
{
    const int t = (int)blockIdx.x * 256 + (int)threadIdx.x;  // float4 index
    const size_t off = (size_t)t * 4;
    const int be = t >> 6;            // D/4 = 64 float4 per (b,e) row

    f32x4 s = {};
    #pragma unroll
    for (int k = 0; k < SPLITK; ++k) {
        const f32x4 v = *(const f32x4*)(ws + (size_t)k * SLICE_ELEMS + off);
        s += v;
    }
    const float il = 1.0f / lens[be];
    s *= il;
    *(f32x4*)(out + off) = s;
}

extern "C" void kernel_launch(void* const* d_in, const int* in_sizes, int n_in,
                              void* d_out, int out_size, void* d_ws, size_t ws_size,
                              hipStream_t stream) {
    const float* doc  = (const float*)d_in[0];  // doc_state [B,L,D]
    const float* map  = (const float*)d_in[1];  // entity_mapping [B,E,L]
    const float* lens = (const float*)d_in[2];  // entity_lens [B,E]
    float* out = (float*)d_out;                 // [B,E,D] fp32
    float* ws  = (float*)d_ws;                  // needs 32 MB (SPLITK slices)

    // No memset needed: stage 1 fully writes every ws element, stage 2 fully
    // overwrites out.
    dim3 grid1(SPLITK * 8 * B_N);   // 512 blocks: 8 tiles x 8 b x 8 kc
    mp_gemm<<<grid1, NTHREADS, 0, stream>>>(doc, map, ws);

    dim3 grid2(SLICE_ELEMS / 4 / 256);  // 1024 blocks
    mp_reduce<<<grid2, 256, 0, stream>>>(ws, lens, out);
}